// Round 1
// baseline (109.614 us; speedup 1.0000x reference)
//
#include <hip/hip_runtime.h>

// YOLOv3 loss: B=32, A=3, S=52, C=80
constexpr int Bb = 32, Aa = 3, Ss = 52, Cc = 80;
constexpr int NCELL = Bb * Aa * Ss * Ss;       // 259584
constexpr int PSTR  = 5 + Cc;                  // 85 floats per cell in predictions
constexpr float L_CLASS = 1.0f, L_NOOBJ = 10.0f, L_OBJ = 1.0f, L_BOX = 10.0f;

__device__ __forceinline__ float bce_logits(float x, float z) {
    // max(x,0) - x*z + log1p(exp(-|x|))
    return fmaxf(x, 0.0f) - x * z + log1pf(expf(-fabsf(x)));
}

// acc layout: [0]=n_obj [1]=n_noobj [2]=noobj_sum [3]=obj_sum [4]=box_sum [5]=cls_sum
__global__ void __launch_bounds__(256) yolo_main(const float* __restrict__ pred,
                                                 const float* __restrict__ tgt,
                                                 const float* __restrict__ anchors,
                                                 float* __restrict__ acc) {
    float a_nobj = 0.f, a_nnoobj = 0.f, a_noobj = 0.f, a_obj = 0.f, a_box = 0.f, a_cls = 0.f;

    for (int cell = blockIdx.x * blockDim.x + threadIdx.x; cell < NCELL;
         cell += gridDim.x * blockDim.x) {
        const float* t = tgt + (size_t)cell * 6;
        const float* p = pred + (size_t)cell * PSTR;
        float t0 = t[0];
        float p0 = p[0];

        if (t0 == 0.0f) {
            a_nnoobj += 1.0f;
            // bce(p0, 0)
            a_noobj += fmaxf(p0, 0.0f) + log1pf(expf(-fabsf(p0)));
        } else if (t0 == 1.0f) {
            a_nobj += 1.0f;
            int a = (cell / (Ss * Ss)) % Aa;
            float ax = anchors[2 * a], ay = anchors[2 * a + 1];

            float px = p[1], py = p[2], pw = p[3], ph = p[4];
            float tx = t[1], ty = t[2], tw = t[3], th = t[4];

            float sx = 1.0f / (1.0f + expf(-px));
            float sy = 1.0f / (1.0f + expf(-py));
            float ew = expf(pw) * ax;
            float eh = expf(ph) * ay;

            // IOU midpoint: a=(sx,sy,ew,eh) vs b=(tx,ty,tw,th)
            float ax1 = sx - ew * 0.5f, ax2 = sx + ew * 0.5f;
            float ay1 = sy - eh * 0.5f, ay2 = sy + eh * 0.5f;
            float bx1 = tx - tw * 0.5f, bx2 = tx + tw * 0.5f;
            float by1 = ty - th * 0.5f, by2 = ty + th * 0.5f;
            float iw = fmaxf(fminf(ax2, bx2) - fmaxf(ax1, bx1), 0.0f);
            float ih = fmaxf(fminf(ay2, by2) - fmaxf(ay1, by1), 0.0f);
            float inter = iw * ih;
            float area_a = fabsf((ax2 - ax1) * (ay2 - ay1));
            float area_b = fabsf((bx2 - bx1) * (by2 - by1));
            float iou = inter / (area_a + area_b - inter + 1e-6f);

            // object BCE with z = iou (t0 == 1)
            a_obj += bce_logits(p0, iou);

            // box MSE: [sigmoid(xy), wh logits] vs [txy, log(twh/anchor + 1e-16)]
            float dx = sx - tx, dy = sy - ty;
            float dw = pw - logf(tw / ax + 1e-16f);
            float dh = ph - logf(th / ay + 1e-16f);
            a_box += dx * dx + dy * dy + dw * dw + dh * dh;

            // class CE via one-pass online softmax over 80 logits
            int cls = (int)t[5];
            float m = -INFINITY, s = 0.0f, lc = 0.0f;
            for (int c = 0; c < Cc; ++c) {
                float v = p[5 + c];
                if (c == cls) lc = v;
                if (v > m) {
                    s = s * expf(m - v) + 1.0f;
                    m = v;
                } else {
                    s += expf(v - m);
                }
            }
            a_cls += (m + logf(s)) - lc;
        }
    }

    // wave (64-lane) shuffle reduce, then cross-wave via LDS, then 1 atomic/block/acc
    #pragma unroll
    for (int off = 32; off > 0; off >>= 1) {
        a_nobj   += __shfl_down(a_nobj, off, 64);
        a_nnoobj += __shfl_down(a_nnoobj, off, 64);
        a_noobj  += __shfl_down(a_noobj, off, 64);
        a_obj    += __shfl_down(a_obj, off, 64);
        a_box    += __shfl_down(a_box, off, 64);
        a_cls    += __shfl_down(a_cls, off, 64);
    }

    __shared__ float sdata[6][4];  // 4 waves per 256-thread block
    int lane = threadIdx.x & 63;
    int wid  = threadIdx.x >> 6;
    if (lane == 0) {
        sdata[0][wid] = a_nobj;
        sdata[1][wid] = a_nnoobj;
        sdata[2][wid] = a_noobj;
        sdata[3][wid] = a_obj;
        sdata[4][wid] = a_box;
        sdata[5][wid] = a_cls;
    }
    __syncthreads();
    if (threadIdx.x == 0) {
        float v0 = 0, v1 = 0, v2 = 0, v3 = 0, v4 = 0, v5 = 0;
        int nw = blockDim.x >> 6;
        for (int w = 0; w < nw; ++w) {
            v0 += sdata[0][w]; v1 += sdata[1][w]; v2 += sdata[2][w];
            v3 += sdata[3][w]; v4 += sdata[4][w]; v5 += sdata[5][w];
        }
        atomicAdd(&acc[0], v0);
        atomicAdd(&acc[1], v1);
        atomicAdd(&acc[2], v2);
        atomicAdd(&acc[3], v3);
        atomicAdd(&acc[4], v4);
        atomicAdd(&acc[5], v5);
    }
}

__global__ void yolo_final(const float* __restrict__ acc, float* __restrict__ out) {
    float n_obj   = fmaxf(acc[0], 1.0f);
    float n_noobj = fmaxf(acc[1], 1.0f);
    out[0] = L_NOOBJ * acc[2] / n_noobj
           + L_OBJ   * acc[3] / n_obj
           + L_BOX   * acc[4] / (n_obj * 4.0f)
           + L_CLASS * acc[5] / n_obj;
}

extern "C" void kernel_launch(void* const* d_in, const int* in_sizes, int n_in,
                              void* d_out, int out_size, void* d_ws, size_t ws_size,
                              hipStream_t stream) {
    const float* pred = (const float*)d_in[0];
    const float* tgt  = (const float*)d_in[1];
    const float* anc  = (const float*)d_in[2];
    float* out = (float*)d_out;
    float* acc = (float*)d_ws;

    hipMemsetAsync(acc, 0, 6 * sizeof(float), stream);

    const int block = 256;
    const int grid  = (NCELL + block - 1) / block;  // 1014 blocks
    yolo_main<<<grid, block, 0, stream>>>(pred, tgt, anc, acc);
    yolo_final<<<1, 1, 0, stream>>>(acc, out);
}

// Round 2
// 45.319 us; speedup vs baseline: 2.4187x; 2.4187x over previous
//
#include <hip/hip_runtime.h>

// YOLOv3 loss: B=32, A=3, S=52, C=80
constexpr int Aa = 3, Ss = 52, Cc = 80;
constexpr int NCELL = 32 * Aa * Ss * Ss;       // 259584 (divisible by 4)
constexpr int PSTR  = 5 + Cc;                  // 85 floats per cell
constexpr int G     = 4;                       // cells per thread
constexpr float L_CLASS = 1.0f, L_NOOBJ = 10.0f, L_OBJ = 1.0f, L_BOX = 10.0f;

__device__ __forceinline__ float bce_logits(float x, float z) {
    return fmaxf(x, 0.0f) - x * z + log1pf(expf(-fabsf(x)));
}

// acc layout: [0]=n_obj [1]=n_noobj [2]=noobj_sum [3]=obj_sum [4]=box_sum [5]=cls_sum
__global__ void __launch_bounds__(256) yolo_main(const float* __restrict__ pred,
                                                 const float* __restrict__ tgt,
                                                 const float* __restrict__ anchors,
                                                 float* __restrict__ acc) {
    const int lane = threadIdx.x & 63;
    const int tid  = blockIdx.x * blockDim.x + threadIdx.x;
    const int base = tid * G;
    const bool valid = base < NCELL;   // NCELL % 4 == 0, so valid => all 4 cells valid

    float a_nobj = 0.f, a_nnoobj = 0.f, a_noobj = 0.f, a_obj = 0.f, a_box = 0.f, a_cls = 0.f;

    // --- issue all loads up front (ILP) ---
    float tf[6 * G];   // 4 cells x 6 target floats, via 6 aligned float4 loads
    float p0[G];       // objectness logits, 4 independent stride-340B gathers
    if (valid) {
        const float4* tp = reinterpret_cast<const float4*>(tgt + (size_t)base * 6);
        #pragma unroll
        for (int i = 0; i < 6; ++i) {
            float4 v = tp[i];
            tf[4 * i] = v.x; tf[4 * i + 1] = v.y; tf[4 * i + 2] = v.z; tf[4 * i + 3] = v.w;
        }
        #pragma unroll
        for (int g = 0; g < G; ++g) p0[g] = pred[(size_t)(base + g) * PSTR];
    }

    #pragma unroll
    for (int g = 0; g < G; ++g) {
        const int cell = base + g;
        const float t0  = valid ? tf[g * 6] : -1.0f;   // -1 => neither obj nor noobj
        const float p0g = valid ? p0[g] : 0.0f;
        const bool is_obj = (t0 == 1.0f);

        if (t0 == 0.0f) {
            a_nnoobj += 1.0f;
            a_noobj  += fmaxf(p0g, 0.0f) + log1pf(expf(-fabsf(p0g)));
        }

        int clsg = 0;
        if (is_obj) {
            a_nobj += 1.0f;
            const float* p = pred + (size_t)cell * PSTR;
            const int a = (cell / (Ss * Ss)) % Aa;
            const float ax = anchors[2 * a], ay = anchors[2 * a + 1];

            float px = p[1], py = p[2], pw = p[3], ph = p[4];
            float tx = tf[g * 6 + 1], ty = tf[g * 6 + 2];
            float tw = tf[g * 6 + 3], th = tf[g * 6 + 4];

            float sx = 1.0f / (1.0f + expf(-px));
            float sy = 1.0f / (1.0f + expf(-py));
            float ew = expf(pw) * ax;
            float eh = expf(ph) * ay;

            float ax1 = sx - ew * 0.5f, ax2 = sx + ew * 0.5f;
            float ay1 = sy - eh * 0.5f, ay2 = sy + eh * 0.5f;
            float bx1 = tx - tw * 0.5f, bx2 = tx + tw * 0.5f;
            float by1 = ty - th * 0.5f, by2 = ty + th * 0.5f;
            float iw = fmaxf(fminf(ax2, bx2) - fmaxf(ax1, bx1), 0.0f);
            float ih = fmaxf(fminf(ay2, by2) - fmaxf(ay1, by1), 0.0f);
            float inter = iw * ih;
            float area_a = fabsf((ax2 - ax1) * (ay2 - ay1));
            float area_b = fabsf((bx2 - bx1) * (by2 - by1));
            float iou = inter / (area_a + area_b - inter + 1e-6f);

            a_obj += bce_logits(p0g, iou);

            float dx = sx - tx, dy = sy - ty;
            float dw = pw - logf(tw / ax + 1e-16f);
            float dh = ph - logf(th / ay + 1e-16f);
            a_box += dx * dx + dy * dy + dw * dw + dh * dh;

            clsg = (int)tf[g * 6 + 5];
        }

        // --- wave-parallel class CE: all 64 lanes cooperate per object cell ---
        unsigned long long m = __ballot(is_obj);
        while (m) {
            const int src = __ffsll((unsigned long long)m) - 1;
            m &= m - 1;
            const int ocell = __shfl(cell, src, 64);
            const int ocls  = __shfl(clsg, src, 64);
            const float* row = pred + (size_t)ocell * PSTR + 5;
            // 80 contiguous logits: lane reads index lane, and lanes 0-15 read 64+lane
            float v0 = row[lane];
            float v1 = (lane < 16) ? row[64 + lane] : -INFINITY;
            float mx = fmaxf(v0, v1);
            #pragma unroll
            for (int off = 32; off; off >>= 1) mx = fmaxf(mx, __shfl_xor(mx, off, 64));
            float e = expf(v0 - mx) + ((lane < 16) ? expf(v1 - mx) : 0.0f);
            #pragma unroll
            for (int off = 32; off; off >>= 1) e += __shfl_xor(e, off, 64);
            float lc = (ocls < 64) ? __shfl(v0, ocls, 64) : __shfl(v1, ocls - 64, 64);
            if (lane == src) a_cls += (mx + logf(e)) - lc;
        }
    }

    // --- wave shuffle reduce -> LDS -> 1 atomic per block per accumulator ---
    #pragma unroll
    for (int off = 32; off > 0; off >>= 1) {
        a_nobj   += __shfl_down(a_nobj, off, 64);
        a_nnoobj += __shfl_down(a_nnoobj, off, 64);
        a_noobj  += __shfl_down(a_noobj, off, 64);
        a_obj    += __shfl_down(a_obj, off, 64);
        a_box    += __shfl_down(a_box, off, 64);
        a_cls    += __shfl_down(a_cls, off, 64);
    }

    __shared__ float sdata[6][4];
    const int wid = threadIdx.x >> 6;
    if (lane == 0) {
        sdata[0][wid] = a_nobj;
        sdata[1][wid] = a_nnoobj;
        sdata[2][wid] = a_noobj;
        sdata[3][wid] = a_obj;
        sdata[4][wid] = a_box;
        sdata[5][wid] = a_cls;
    }
    __syncthreads();
    if (threadIdx.x == 0) {
        float v0 = 0, v1 = 0, v2 = 0, v3 = 0, v4 = 0, v5 = 0;
        const int nw = blockDim.x >> 6;
        for (int w = 0; w < nw; ++w) {
            v0 += sdata[0][w]; v1 += sdata[1][w]; v2 += sdata[2][w];
            v3 += sdata[3][w]; v4 += sdata[4][w]; v5 += sdata[5][w];
        }
        atomicAdd(&acc[0], v0);
        atomicAdd(&acc[1], v1);
        atomicAdd(&acc[2], v2);
        atomicAdd(&acc[3], v3);
        atomicAdd(&acc[4], v4);
        atomicAdd(&acc[5], v5);
    }
}

__global__ void yolo_final(const float* __restrict__ acc, float* __restrict__ out) {
    float n_obj   = fmaxf(acc[0], 1.0f);
    float n_noobj = fmaxf(acc[1], 1.0f);
    out[0] = L_NOOBJ * acc[2] / n_noobj
           + L_OBJ   * acc[3] / n_obj
           + L_BOX   * acc[4] / (n_obj * 4.0f)
           + L_CLASS * acc[5] / n_obj;
}

extern "C" void kernel_launch(void* const* d_in, const int* in_sizes, int n_in,
                              void* d_out, int out_size, void* d_ws, size_t ws_size,
                              hipStream_t stream) {
    const float* pred = (const float*)d_in[0];
    const float* tgt  = (const float*)d_in[1];
    const float* anc  = (const float*)d_in[2];
    float* out = (float*)d_out;
    float* acc = (float*)d_ws;

    hipMemsetAsync(acc, 0, 6 * sizeof(float), stream);

    const int block = 256;
    const int nthreads = NCELL / G;                      // 64896
    const int grid = (nthreads + block - 1) / block;     // 254 blocks
    yolo_main<<<grid, block, 0, stream>>>(pred, tgt, anc, acc);
    yolo_final<<<1, 1, 0, stream>>>(acc, out);
}